// Round 3
// baseline (713.549 us; speedup 1.0000x reference)
//
#include <hip/hip_runtime.h>
#include <hip/hip_bf16.h>
#include <hip/hip_fp16.h>

// LightGCN 3-hop propagation, 150k nodes, 4.8M edges, EMB=64.
// Round 10 (session R2):
//  - hop: predicated full-width 16-edge chunks (no serial remainder tail;
//    OOB slots clamp csr index to e-1 and zero w -> no extra traffic).
//  - hop: depth-2 software pipeline with static A/B buffers (16 gathers +
//    8 csr loads in flight per wave, no register copies).
//  - hop: non-temporal csr/E0/H1 loads (38MB/hop streams stop evicting the
//    19.2MB gather working set from L2).
// R9 kept: fp16 internal storage for fp32 inputs, packed int2 csr, fused
// epilogue. CSR build unchanged. Keeps dtype flag + atomic fallback.

#define NUM_USERS 100000
#define NUM_ITEMS 50000
#define N_NODES   150000
#define EMB       64
#define N_EDGES   4800000
#define NODE_ELEMS (N_NODES * EMB)   // 9,600,000
#define U_ELEMS    (NUM_USERS * EMB) // 6,400,000
#define I_ELEMS    (NUM_ITEMS * EMB) // 3,200,000

#define RPB 256                       // rows per bucket (2^8: row>>8, row&255)
#define NB  ((N_NODES + RPB - 1) / RPB)   // 586 buckets
#define EPB 8192                      // edges staged per bin block

typedef __hip_bfloat16 bf16;

// flag bit0: float arrays are bf16 (else fp32). bit1: edge_index int64 (else int32).
__global__ void detect_kernel(const unsigned short* __restrict__ u16,
                              const int* __restrict__ ei32,
                              int* __restrict__ flag,
                              int* __restrict__ bucket_cnt)
{
    __shared__ int s_fp32, s_i32;
    if (threadIdx.x == 0) { s_fp32 = 0; s_i32 = 0; }
    __syncthreads();
    int t = threadIdx.x;
    for (int i = t; i < NB + 1; i += 256) bucket_cnt[i] = 0;
    unsigned short u = u16[t];
    int e = (u >> 7) & 0xFF;
    if (e >= 0xC0) atomicOr(&s_fp32, 1);
    if (t < 64 && ei32[2 * t + 1] != 0) atomicOr(&s_i32, 1);
    __syncthreads();
    if (t == 0) {
        int f = 0;
        if (!s_fp32) f |= 1;
        if (!s_i32)  f |= 2;
        *flag = f;
    }
}

__device__ __forceinline__ int load_row(const int* ei32, int f, size_t e) {
    return (f & 2) ? ei32[2 * e] : ei32[e];
}
__device__ __forceinline__ int load_col(const int* ei32, int f, size_t e) {
    return (f & 2) ? ei32[2 * ((size_t)N_EDGES + e)] : ei32[(size_t)N_EDGES + e];
}
__device__ __forceinline__ float load_w(const void* ew, int f, size_t e) {
    return (f & 1) ? __bfloat162float(((const bf16*)ew)[e]) : ((const float*)ew)[e];
}

// ---------- vectorized init: A (16-bit packed) + passthrough ----------
__global__ void init_vec_kernel(const void* __restrict__ users,
                                const void* __restrict__ items,
                                void* __restrict__ out,
                                void* __restrict__ A,
                                const int* __restrict__ flag)
{
    int g = blockIdx.x * blockDim.x + threadIdx.x;   // NODE_ELEMS/4 threads
    if (g >= NODE_ELEMS / 4) return;
    int g4 = g * 4;
    const bool isb = ((*flag) & 1);
    if (isb) {
        uint2 v;
        if (g4 < U_ELEMS) {
            v = ((const uint2*)users)[g];
            ((uint2*)((bf16*)out + U_ELEMS))[g] = v;
        } else {
            int ii = g - U_ELEMS / 4;
            v = ((const uint2*)items)[ii];
            ((uint2*)((bf16*)out + 2 * (size_t)U_ELEMS + I_ELEMS))[ii] = v;
        }
        ((uint2*)A)[g] = v;            // A stored bf16
    } else {
        float4 v;
        if (g4 < U_ELEMS) {
            v = ((const float4*)users)[g];
            ((float4*)((float*)out + U_ELEMS))[g] = v;
        } else {
            int ii = g - U_ELEMS / 4;
            v = ((const float4*)items)[ii];
            ((float4*)((float*)out + 2 * (size_t)U_ELEMS + I_ELEMS))[ii] = v;
        }
        __half2 ha = __floats2half2_rn(v.x, v.y);
        __half2 hb = __floats2half2_rn(v.z, v.w);
        uint2 u2;
        u2.x = *reinterpret_cast<unsigned int*>(&ha);
        u2.y = *reinterpret_cast<unsigned int*>(&hb);
        ((uint2*)A)[g] = u2;           // A stored fp16 (intermediates 16-bit)
    }
}

// ---------- binned CSR build ----------

__global__ void bucket_hist_kernel(const int* __restrict__ ei32,
                                   int* __restrict__ bucket_cnt,
                                   const int* __restrict__ flag)
{
    __shared__ int h[NB];
    for (int i = threadIdx.x; i < NB; i += blockDim.x) h[i] = 0;
    __syncthreads();
    const int f = *flag;
    const size_t stride = (size_t)gridDim.x * blockDim.x;
    for (size_t e = (size_t)blockIdx.x * blockDim.x + threadIdx.x; e < N_EDGES; e += stride)
        atomicAdd(&h[load_row(ei32, f, e) >> 8], 1);
    __syncthreads();
    for (int i = threadIdx.x; i < NB; i += blockDim.x)
        if (h[i]) atomicAdd(&bucket_cnt[i], h[i]);
}

__global__ void bucket_scan_kernel(const int* __restrict__ bucket_cnt,
                                   int* __restrict__ bucket_base,
                                   int* __restrict__ bucket_off)
{
    __shared__ int ls[16];
    const int t = threadIdx.x;           // 1024 threads, NB <= 1024
    const int lane = t & 63, wv = t >> 6;
    int x = (t < NB) ? bucket_cnt[t] : 0;
    int v = x;
    #pragma unroll
    for (int d = 1; d < 64; d <<= 1) { int y = __shfl_up(v, d, 64); if (lane >= d) v += y; }
    if (lane == 63) ls[wv] = v;
    __syncthreads();
    if (wv == 0 && lane < 16) {
        int s = ls[lane];
        #pragma unroll
        for (int d = 1; d < 16; d <<= 1) { int y = __shfl_up(s, d, 64); if (lane >= d) s += y; }
        ls[lane] = s;
    }
    __syncthreads();
    int waveoff = wv ? ls[wv - 1] : 0;
    int excl = waveoff + v - x;
    if (t < NB) { bucket_base[t] = excl; bucket_off[t] = excl; }
    if (t == 0) bucket_base[NB] = ls[15];   // == N_EDGES
}

// stage 8192 edges in LDS, rank by bucket, write bucket-contiguous runs.
__global__ __launch_bounds__(1024) void bin_kernel(const int* __restrict__ ei32,
                                                   const void* __restrict__ ew,
                                                   int* __restrict__ bucket_off,
                                                   int2* __restrict__ rec,
                                                   const int* __restrict__ flag)
{
    __shared__ int2 stage[EPB];            // 64 KB
    __shared__ unsigned short bof[EPB];    // 16 KB
    __shared__ int hist[NB], excl0[NB], rank_[NB], gbase[NB];
    __shared__ int ls[16];
    const int t = threadIdx.x;
    const size_t base_e = (size_t)blockIdx.x * EPB;
    const int cnt = (int)(((base_e + EPB) <= N_EDGES) ? EPB : (N_EDGES - base_e));
    for (int i = t; i < NB; i += 1024) hist[i] = 0;
    __syncthreads();
    const int f = *flag;
    int  mybkt[8];
    int2 myrec[8];
    #pragma unroll
    for (int k = 0; k < 8; ++k) {
        int idx = k * 1024 + t;
        if (idx < cnt) {
            size_t e = base_e + idx;
            int row = load_row(ei32, f, e);
            int col = load_col(ei32, f, e);
            float w = load_w(ew, f, e);
            mybkt[k] = row >> 8;
            myrec[k] = make_int2(col | ((row & 255) << 18), __float_as_int(w));
            atomicAdd(&hist[mybkt[k]], 1);
        } else mybkt[k] = -1;
    }
    __syncthreads();
    {   // scan hist[0..NB) -> excl0, rank_
        const int lane = t & 63, wv = t >> 6;
        int x = (t < NB) ? hist[t] : 0;
        int v = x;
        #pragma unroll
        for (int d = 1; d < 64; d <<= 1) { int y = __shfl_up(v, d, 64); if (lane >= d) v += y; }
        if (lane == 63) ls[wv] = v;
        __syncthreads();
        if (wv == 0 && lane < 16) {
            int s = ls[lane];
            #pragma unroll
            for (int d = 1; d < 16; d <<= 1) { int y = __shfl_up(s, d, 64); if (lane >= d) s += y; }
            ls[lane] = s;
        }
        __syncthreads();
        int waveoff = wv ? ls[wv - 1] : 0;
        int excl = waveoff + v - x;
        if (t < NB) { excl0[t] = excl; rank_[t] = excl; }
    }
    __syncthreads();
    if (t < NB && hist[t] > 0) gbase[t] = atomicAdd(&bucket_off[t], hist[t]);
    else if (t < NB)           gbase[t] = 0;
    #pragma unroll
    for (int k = 0; k < 8; ++k) {
        if (mybkt[k] >= 0) {
            int p = atomicAdd(&rank_[mybkt[k]], 1);
            stage[p] = myrec[k];
            bof[p]   = (unsigned short)mybkt[k];
        }
    }
    __syncthreads();
    for (int s = t; s < cnt; s += 1024) {
        int b = bof[s];
        rec[gbase[b] + (s - excl0[b])] = stage[s];   // coalesced runs per bucket
    }
}

// one block per bucket: local row hist + scan -> rowptr; scatter packed
// (col,w) csr within an L2-resident window.
__global__ void local_fill_kernel(const int* __restrict__ bucket_base,
                                  const int2* __restrict__ rec,
                                  int2* __restrict__ csr,
                                  int* __restrict__ rowptr)
{
    __shared__ int hist[RPB], off[RPB], ls[4];
    const int b = blockIdx.x, t = threadIdx.x;      // 256 threads
    const int lo = bucket_base[b], hi = bucket_base[b + 1];
    const int rows = (N_NODES - b * RPB < RPB) ? (N_NODES - b * RPB) : RPB;
    hist[t] = 0;
    __syncthreads();
    for (int s = lo + t; s < hi; s += 256)
        atomicAdd(&hist[rec[s].x >> 18], 1);
    __syncthreads();
    const int lane = t & 63, wv = t >> 6;
    int x = hist[t];
    int v = x;
    #pragma unroll
    for (int d = 1; d < 64; d <<= 1) { int y = __shfl_up(v, d, 64); if (lane >= d) v += y; }
    if (lane == 63) ls[wv] = v;
    __syncthreads();
    if (wv == 0 && lane < 4) {
        int s = ls[lane];
        #pragma unroll
        for (int d = 1; d < 4; d <<= 1) { int y = __shfl_up(s, d, 64); if (lane >= d) s += y; }
        ls[lane] = s;
    }
    __syncthreads();
    int waveoff = wv ? ls[wv - 1] : 0;
    int excl = waveoff + v - x;
    if (t < rows) rowptr[b * RPB + t] = lo + excl;
    off[t] = lo + excl;
    if (b == NB - 1 && t == 0) rowptr[N_NODES] = N_EDGES;
    __syncthreads();
    for (int s = lo + t; s < hi; s += 256) {
        int2 r = rec[s];
        int rl = r.x >> 18;
        int pos = atomicAdd(&off[rl], 1);
        csr[pos] = make_int2(r.x & 0x3FFFF, r.y);   // packed (col, w-bits)
    }
}

// ---------- gather hop core: predicated 16-edge chunks, depth-2 pipeline ----
// lanes 0-31 even edges, 32-63 odd edges; lane owns dims {2*hl, 2*hl+1} as
// one packed uint (bf16 or fp16). OOB slots clamp csr index to e-1, w=0.

template <bool ISB>
__device__ __forceinline__ void gather_row(const int2* __restrict__ csr,
                                           const unsigned int* __restrict__ p,
                                           int s, int e, int half, int hl,
                                           float& alo_o, float& ahi_o)
{
    float lo[4] = {0.f, 0.f, 0.f, 0.f};
    float hi[4] = {0.f, 0.f, 0.f, 0.f};
    int2 cwA[8], cwB[8];
    unsigned int vA[8], vB[8];
    const int len = e - s;
    const int nch = (len + 15) >> 4;

    auto LD = [&](int c, int2* cw) {
        #pragma unroll
        for (int u = 0; u < 8; ++u) {
            int idx = s + c * 16 + 2 * u + half;
            int j = (idx < e) ? idx : (e - 1);
            long long raw = __builtin_nontemporal_load(
                reinterpret_cast<const long long*>(csr) + j);
            int2 t;
            t.x = (int)(unsigned int)(raw & 0xffffffffll);
            t.y = (int)(raw >> 32);
            if (idx >= e) t.y = 0;        // w = 0 for padding slots
            cw[u] = t;
        }
    };
    auto GA = [&](const int2* cw, unsigned int* v) {
        #pragma unroll
        for (int u = 0; u < 8; ++u)
            v[u] = p[(size_t)((unsigned int)cw[u].x * 32u + hl)];
    };
    auto FM = [&](const int2* cw, const unsigned int* v) {
        #pragma unroll
        for (int u = 0; u < 8; ++u) {
            float w = __int_as_float(cw[u].y);
            float fx, fy;
            if (ISB) {
                fx = __uint_as_float(v[u] << 16);
                fy = __uint_as_float(v[u] & 0xffff0000u);
            } else {
                float2 f = __half22float2(*reinterpret_cast<const __half2*>(&v[u]));
                fx = f.x; fy = f.y;
            }
            lo[u & 3] = fmaf(w, fx, lo[u & 3]);
            hi[u & 3] = fmaf(w, fy, hi[u & 3]);
        }
    };

    if (nch > 0) {
        LD(0, cwA); GA(cwA, vA);
        int c = 0;
        while (true) {
            if (c + 1 < nch) { LD(c + 1, cwB); GA(cwB, vB); }
            FM(cwA, vA);
            if (++c >= nch) break;
            if (c + 1 < nch) { LD(c + 1, cwA); GA(cwA, vA); }
            FM(cwB, vB);
            if (++c >= nch) break;
        }
    }
    alo_o = (lo[0] + lo[1]) + (lo[2] + lo[3]);
    ahi_o = (hi[0] + hi[1]) + (hi[2] + hi[3]);
}

// LAST fuses epilogue: out = (emb0 + h1 + h2 + h3)/4.
template <bool LAST>
__global__ void hop_kernel(const int* __restrict__ rowptr,
                           const int2* __restrict__ csr,
                           const void* __restrict__ prev,
                           void* __restrict__ next,
                           const void* __restrict__ E0,   // emb0 (LAST only)
                           const void* __restrict__ H1,   // h1   (LAST only)
                           void* __restrict__ out,
                           const int* __restrict__ flag)
{
    int row  = blockIdx.x * (blockDim.x >> 6) + (threadIdx.x >> 6);
    if (row >= N_NODES) return;
    const int half = (threadIdx.x >> 5) & 1;
    const int hl   = threadIdx.x & 31;
    const bool isb = ((*flag) & 1);
    const int s = rowptr[row], e = rowptr[row + 1];
    const unsigned int* p = (const unsigned int*)prev;
    float alo, ahi;
    if (isb) gather_row<true >(csr, p, s, e, half, hl, alo, ahi);
    else     gather_row<false>(csr, p, s, e, half, hl, alo, ahi);
    alo += __shfl_xor(alo, 32);          // combine even/odd edge halves
    ahi += __shfl_xor(ahi, 32);
    if (half) return;                    // half 0 writes the full row
    size_t o32 = (size_t)row * 32 + hl;  // index in 2-element units
    if (LAST) {
        size_t oo = o32 + ((row < NUM_USERS) ? 0 : (size_t)(U_ELEMS / 2));
        unsigned int e0u = __builtin_nontemporal_load((const unsigned int*)E0 + o32);
        unsigned int h1u = __builtin_nontemporal_load((const unsigned int*)H1 + o32);
        unsigned int h2u = ((const unsigned int*)prev)[o32];
        if (isb) {
            float vlo = (__uint_as_float(e0u << 16) + __uint_as_float(h1u << 16) +
                         __uint_as_float(h2u << 16) + alo) * 0.25f;
            float vhi = (__uint_as_float(e0u & 0xffff0000u) + __uint_as_float(h1u & 0xffff0000u) +
                         __uint_as_float(h2u & 0xffff0000u) + ahi) * 0.25f;
            bf16 blo = __float2bfloat16(vlo), bhi = __float2bfloat16(vhi);
            ((unsigned int*)out)[oo] =
                ((unsigned int)(*reinterpret_cast<unsigned short*>(&bhi)) << 16) |
                (*reinterpret_cast<unsigned short*>(&blo));
        } else {
            float2 e0f = __half22float2(*reinterpret_cast<const __half2*>(&e0u));
            float2 h1f = __half22float2(*reinterpret_cast<const __half2*>(&h1u));
            float2 h2f = __half22float2(*reinterpret_cast<const __half2*>(&h2u));
            float2 v;
            v.x = (e0f.x + h1f.x + h2f.x + alo) * 0.25f;
            v.y = (e0f.y + h1f.y + h2f.y + ahi) * 0.25f;
            ((float2*)out)[oo] = v;
        }
    } else {
        if (isb) {
            bf16 blo = __float2bfloat16(alo), bhi = __float2bfloat16(ahi);
            ((unsigned int*)next)[o32] =
                ((unsigned int)(*reinterpret_cast<unsigned short*>(&bhi)) << 16) |
                (*reinterpret_cast<unsigned short*>(&blo));
        } else {
            __half2 h = __floats2half2_rn(alo, ahi);
            ((unsigned int*)next)[o32] = *reinterpret_cast<unsigned int*>(&h);
        }
    }
}

// ---------- R3 atomic fallback ----------

__global__ void init_kernel(const void* __restrict__ users,
                            const void* __restrict__ items,
                            void* __restrict__ out,
                            float* __restrict__ A,
                            float* __restrict__ B,
                            float* __restrict__ ACC,
                            const int* __restrict__ flag)
{
    int gid = blockIdx.x * blockDim.x + threadIdx.x;
    if (gid >= NODE_ELEMS) return;
    const bool isb = ((*flag) & 1);
    float v;
    if (gid < U_ELEMS) {
        if (isb) { bf16 b = ((const bf16*)users)[gid]; v = __bfloat162float(b); ((bf16*)out)[U_ELEMS + gid] = b; }
        else     { float fv = ((const float*)users)[gid]; v = fv; ((float*)out)[U_ELEMS + gid] = fv; }
    } else {
        int ii = gid - U_ELEMS;
        if (isb) { bf16 b = ((const bf16*)items)[ii]; v = __bfloat162float(b); ((bf16*)out)[2 * U_ELEMS + I_ELEMS + ii] = b; }
        else     { float fv = ((const float*)items)[ii]; v = fv; ((float*)out)[2 * U_ELEMS + I_ELEMS + ii] = fv; }
    }
    A[gid]   = v;
    B[gid]   = 0.0f;
    ACC[gid] = v;
}

__global__ void finalize_kernel(const float* __restrict__ acc,
                                void* __restrict__ out,
                                const int* __restrict__ flag)
{
    int gid = blockIdx.x * blockDim.x + threadIdx.x;
    if (gid >= NODE_ELEMS) return;
    const bool isb = ((*flag) & 1);
    float v = acc[gid] * 0.25f;
    size_t o = (gid < U_ELEMS) ? (size_t)gid : (size_t)(2 * U_ELEMS + (gid - U_ELEMS));
    if (isb) ((bf16*)out)[o]  = __float2bfloat16(v);
    else     ((float*)out)[o] = v;
}

__global__ void scatter_kernel(const int* __restrict__ ei32,
                               const void* __restrict__ ew,
                               const float* __restrict__ prev,
                               float* __restrict__ next,
                               const int* __restrict__ flag)
{
    int gid = blockIdx.x * blockDim.x + threadIdx.x;
    if (gid >= N_EDGES * 16) return;
    const int f = *flag;
    int e = gid >> 4;
    int j = (gid & 15) << 2;
    int row = load_row(ei32, f, e);
    int col = load_col(ei32, f, e);
    float w = load_w(ew, f, e);
    const float4 v = *reinterpret_cast<const float4*>(prev + (size_t)col * EMB + j);
    float* dst = next + (size_t)row * EMB + j;
    unsafeAtomicAdd(dst + 0, w * v.x);
    unsafeAtomicAdd(dst + 1, w * v.y);
    unsafeAtomicAdd(dst + 2, w * v.z);
    unsafeAtomicAdd(dst + 3, w * v.w);
}

__global__ void accum_zero_kernel(float* __restrict__ acc,
                                  const float* __restrict__ next,
                                  float* __restrict__ prevz)
{
    int gid = blockIdx.x * blockDim.x + threadIdx.x;
    if (gid >= NODE_ELEMS) return;
    acc[gid] += next[gid];
    prevz[gid] = 0.0f;
}

__global__ void sentinel_kernel(unsigned int* __restrict__ out, int nwords)
{
    int gid = blockIdx.x * blockDim.x + threadIdx.x;
    if (gid < nwords) out[gid] = 0x447A447Au;
}

extern "C" void kernel_launch(void* const* d_in, const int* in_sizes, int n_in,
                              void* d_out, int out_size, void* d_ws, size_t ws_size,
                              hipStream_t stream)
{
    const void* users = d_in[0];
    const void* items = d_in[1];
    const int*  ei32  = (const int*)d_in[2];
    const void* ew    = d_in[3];

    char* wsb  = (char*)d_ws;
    int*  flag = (int*)wsb;
    float* A   = (float*)(wsb + 256);              // fp32-sized; holds 16-bit in CSR path
    float* B   = A + (size_t)NODE_ELEMS;           // h1 buffer; aliases rec
    float* ACC = B + (size_t)NODE_ELEMS;           // h2 buffer in CSR path
    char* p    = (char*)(ACC + (size_t)NODE_ELEMS);
    int*  rowptr      = (int*)p;  p += (N_NODES + 4) * sizeof(int);
    int*  bucket_cnt  = (int*)p;  p += (NB + 2) * sizeof(int);
    int*  bucket_base = (int*)p;  p += (NB + 2) * sizeof(int);
    int*  bucket_off  = (int*)p;  p += (NB + 2) * sizeof(int);
    int2* csr         = (int2*)p; p += (size_t)N_EDGES * sizeof(int2);  // packed (col,w)
    int2* rec         = (int2*)B;                  // alias: dead before hop1 writes B

    const size_t need_csr    = (size_t)(p - wsb);                  // ~154.4 MB
    const size_t need_atomic = 256 + 3 * (size_t)NODE_ELEMS * sizeof(float);
    const int BLK = 256;
    const int node_blocks = (NODE_ELEMS + BLK - 1) / BLK;
    const int vec_blocks  = (NODE_ELEMS / 4 + BLK - 1) / BLK;
    const int row_blocks  = (N_NODES + 3) / 4;       // 4 rows (waves) per block
    const int bin_blocks  = (N_EDGES + EPB - 1) / EPB;   // 586

    if (ws_size >= need_csr) {
        float* C = ACC;   // h2 buffer
        detect_kernel<<<1, BLK, 0, stream>>>((const unsigned short*)users, ei32, flag, bucket_cnt);
        init_vec_kernel<<<vec_blocks, BLK, 0, stream>>>(users, items, d_out, A, flag);
        bucket_hist_kernel<<<1024, BLK, 0, stream>>>(ei32, bucket_cnt, flag);
        bucket_scan_kernel<<<1, 1024, 0, stream>>>(bucket_cnt, bucket_base, bucket_off);
        bin_kernel<<<bin_blocks, 1024, 0, stream>>>(ei32, ew, bucket_off, rec, flag);
        local_fill_kernel<<<NB, RPB, 0, stream>>>(bucket_base, rec, csr, rowptr);

        // hop1: A(emb0) -> B(h1); hop2: B -> C(h2); hop3: C -> out, fusing
        // out = (A + B + C + h3)/4 in the epilogue.
        hop_kernel<false><<<row_blocks, BLK, 0, stream>>>(rowptr, csr, A, B, nullptr, nullptr, nullptr, flag);
        hop_kernel<false><<<row_blocks, BLK, 0, stream>>>(rowptr, csr, B, C, nullptr, nullptr, nullptr, flag);
        hop_kernel<true ><<<row_blocks, BLK, 0, stream>>>(rowptr, csr, C, nullptr, A, B, d_out, flag);
    } else if (ws_size >= need_atomic) {
        const int sedge_blocks = (N_EDGES * 16 + BLK - 1) / BLK;
        detect_kernel<<<1, BLK, 0, stream>>>((const unsigned short*)users, ei32, flag, bucket_cnt);
        init_kernel<<<node_blocks, BLK, 0, stream>>>(users, items, d_out, A, B, ACC, flag);
        float* prev = A;
        float* nxt  = B;
        for (int h = 0; h < 3; ++h) {
            scatter_kernel<<<sedge_blocks, BLK, 0, stream>>>(ei32, ew, prev, nxt, flag);
            accum_zero_kernel<<<node_blocks, BLK, 0, stream>>>(ACC, nxt, prev);
            float* t = prev; prev = nxt; nxt = t;
        }
        finalize_kernel<<<node_blocks, BLK, 0, stream>>>(ACC, d_out, flag);
    } else {
        int nwords = out_size / 2;
        sentinel_kernel<<<(nwords + BLK - 1) / BLK, BLK, 0, stream>>>((unsigned int*)d_out, nwords);
    }
}

// Round 4
// 654.773 us; speedup vs baseline: 1.0898x; 1.0898x over previous
//
#include <hip/hip_runtime.h>
#include <hip/hip_bf16.h>
#include <hip/hip_fp16.h>

// LightGCN 3-hop propagation, 150k nodes, 4.8M edges, EMB=64.
// Round 11 (session R3):
//  - hop: revert R2's per-chunk predication (it padded every chunk and added
//    clamp/unpack VALU: 147->167us regression). Main loop is unpredicated
//    16-edge chunks with a TRUE depth-2 pipeline: csr(c+2) + gathers(c+1)
//    in flight while FMA(c) retires (~16 gathers + 8 csr outstanding/wave).
//  - hop tail: ONE predicated 16-slot step per row (index clamped to e-1,
//    w=0) replaces the serial 2-edge loop (~4 dependent latencies -> 1).
// R9 kept: fp16 internal storage for fp32 inputs, packed int2 csr, fused
// epilogue. CSR build unchanged. Keeps dtype flag + atomic fallback.

#define NUM_USERS 100000
#define NUM_ITEMS 50000
#define N_NODES   150000
#define EMB       64
#define N_EDGES   4800000
#define NODE_ELEMS (N_NODES * EMB)   // 9,600,000
#define U_ELEMS    (NUM_USERS * EMB) // 6,400,000
#define I_ELEMS    (NUM_ITEMS * EMB) // 3,200,000

#define RPB 256                       // rows per bucket (2^8: row>>8, row&255)
#define NB  ((N_NODES + RPB - 1) / RPB)   // 586 buckets
#define EPB 8192                      // edges staged per bin block

typedef __hip_bfloat16 bf16;

// flag bit0: float arrays are bf16 (else fp32). bit1: edge_index int64 (else int32).
__global__ void detect_kernel(const unsigned short* __restrict__ u16,
                              const int* __restrict__ ei32,
                              int* __restrict__ flag,
                              int* __restrict__ bucket_cnt)
{
    __shared__ int s_fp32, s_i32;
    if (threadIdx.x == 0) { s_fp32 = 0; s_i32 = 0; }
    __syncthreads();
    int t = threadIdx.x;
    for (int i = t; i < NB + 1; i += 256) bucket_cnt[i] = 0;
    unsigned short u = u16[t];
    int e = (u >> 7) & 0xFF;
    if (e >= 0xC0) atomicOr(&s_fp32, 1);
    if (t < 64 && ei32[2 * t + 1] != 0) atomicOr(&s_i32, 1);
    __syncthreads();
    if (t == 0) {
        int f = 0;
        if (!s_fp32) f |= 1;
        if (!s_i32)  f |= 2;
        *flag = f;
    }
}

__device__ __forceinline__ int load_row(const int* ei32, int f, size_t e) {
    return (f & 2) ? ei32[2 * e] : ei32[e];
}
__device__ __forceinline__ int load_col(const int* ei32, int f, size_t e) {
    return (f & 2) ? ei32[2 * ((size_t)N_EDGES + e)] : ei32[(size_t)N_EDGES + e];
}
__device__ __forceinline__ float load_w(const void* ew, int f, size_t e) {
    return (f & 1) ? __bfloat162float(((const bf16*)ew)[e]) : ((const float*)ew)[e];
}

// ---------- vectorized init: A (16-bit packed) + passthrough ----------
__global__ void init_vec_kernel(const void* __restrict__ users,
                                const void* __restrict__ items,
                                void* __restrict__ out,
                                void* __restrict__ A,
                                const int* __restrict__ flag)
{
    int g = blockIdx.x * blockDim.x + threadIdx.x;   // NODE_ELEMS/4 threads
    if (g >= NODE_ELEMS / 4) return;
    int g4 = g * 4;
    const bool isb = ((*flag) & 1);
    if (isb) {
        uint2 v;
        if (g4 < U_ELEMS) {
            v = ((const uint2*)users)[g];
            ((uint2*)((bf16*)out + U_ELEMS))[g] = v;
        } else {
            int ii = g - U_ELEMS / 4;
            v = ((const uint2*)items)[ii];
            ((uint2*)((bf16*)out + 2 * (size_t)U_ELEMS + I_ELEMS))[ii] = v;
        }
        ((uint2*)A)[g] = v;            // A stored bf16
    } else {
        float4 v;
        if (g4 < U_ELEMS) {
            v = ((const float4*)users)[g];
            ((float4*)((float*)out + U_ELEMS))[g] = v;
        } else {
            int ii = g - U_ELEMS / 4;
            v = ((const float4*)items)[ii];
            ((float4*)((float*)out + 2 * (size_t)U_ELEMS + I_ELEMS))[ii] = v;
        }
        __half2 ha = __floats2half2_rn(v.x, v.y);
        __half2 hb = __floats2half2_rn(v.z, v.w);
        uint2 u2;
        u2.x = *reinterpret_cast<unsigned int*>(&ha);
        u2.y = *reinterpret_cast<unsigned int*>(&hb);
        ((uint2*)A)[g] = u2;           // A stored fp16 (intermediates 16-bit)
    }
}

// ---------- binned CSR build ----------

__global__ void bucket_hist_kernel(const int* __restrict__ ei32,
                                   int* __restrict__ bucket_cnt,
                                   const int* __restrict__ flag)
{
    __shared__ int h[NB];
    for (int i = threadIdx.x; i < NB; i += blockDim.x) h[i] = 0;
    __syncthreads();
    const int f = *flag;
    const size_t stride = (size_t)gridDim.x * blockDim.x;
    for (size_t e = (size_t)blockIdx.x * blockDim.x + threadIdx.x; e < N_EDGES; e += stride)
        atomicAdd(&h[load_row(ei32, f, e) >> 8], 1);
    __syncthreads();
    for (int i = threadIdx.x; i < NB; i += blockDim.x)
        if (h[i]) atomicAdd(&bucket_cnt[i], h[i]);
}

__global__ void bucket_scan_kernel(const int* __restrict__ bucket_cnt,
                                   int* __restrict__ bucket_base,
                                   int* __restrict__ bucket_off)
{
    __shared__ int ls[16];
    const int t = threadIdx.x;           // 1024 threads, NB <= 1024
    const int lane = t & 63, wv = t >> 6;
    int x = (t < NB) ? bucket_cnt[t] : 0;
    int v = x;
    #pragma unroll
    for (int d = 1; d < 64; d <<= 1) { int y = __shfl_up(v, d, 64); if (lane >= d) v += y; }
    if (lane == 63) ls[wv] = v;
    __syncthreads();
    if (wv == 0 && lane < 16) {
        int s = ls[lane];
        #pragma unroll
        for (int d = 1; d < 16; d <<= 1) { int y = __shfl_up(s, d, 64); if (lane >= d) s += y; }
        ls[lane] = s;
    }
    __syncthreads();
    int waveoff = wv ? ls[wv - 1] : 0;
    int excl = waveoff + v - x;
    if (t < NB) { bucket_base[t] = excl; bucket_off[t] = excl; }
    if (t == 0) bucket_base[NB] = ls[15];   // == N_EDGES
}

// stage 8192 edges in LDS, rank by bucket, write bucket-contiguous runs.
__global__ __launch_bounds__(1024) void bin_kernel(const int* __restrict__ ei32,
                                                   const void* __restrict__ ew,
                                                   int* __restrict__ bucket_off,
                                                   int2* __restrict__ rec,
                                                   const int* __restrict__ flag)
{
    __shared__ int2 stage[EPB];            // 64 KB
    __shared__ unsigned short bof[EPB];    // 16 KB
    __shared__ int hist[NB], excl0[NB], rank_[NB], gbase[NB];
    __shared__ int ls[16];
    const int t = threadIdx.x;
    const size_t base_e = (size_t)blockIdx.x * EPB;
    const int cnt = (int)(((base_e + EPB) <= N_EDGES) ? EPB : (N_EDGES - base_e));
    for (int i = t; i < NB; i += 1024) hist[i] = 0;
    __syncthreads();
    const int f = *flag;
    int  mybkt[8];
    int2 myrec[8];
    #pragma unroll
    for (int k = 0; k < 8; ++k) {
        int idx = k * 1024 + t;
        if (idx < cnt) {
            size_t e = base_e + idx;
            int row = load_row(ei32, f, e);
            int col = load_col(ei32, f, e);
            float w = load_w(ew, f, e);
            mybkt[k] = row >> 8;
            myrec[k] = make_int2(col | ((row & 255) << 18), __float_as_int(w));
            atomicAdd(&hist[mybkt[k]], 1);
        } else mybkt[k] = -1;
    }
    __syncthreads();
    {   // scan hist[0..NB) -> excl0, rank_
        const int lane = t & 63, wv = t >> 6;
        int x = (t < NB) ? hist[t] : 0;
        int v = x;
        #pragma unroll
        for (int d = 1; d < 64; d <<= 1) { int y = __shfl_up(v, d, 64); if (lane >= d) v += y; }
        if (lane == 63) ls[wv] = v;
        __syncthreads();
        if (wv == 0 && lane < 16) {
            int s = ls[lane];
            #pragma unroll
            for (int d = 1; d < 16; d <<= 1) { int y = __shfl_up(s, d, 64); if (lane >= d) s += y; }
            ls[lane] = s;
        }
        __syncthreads();
        int waveoff = wv ? ls[wv - 1] : 0;
        int excl = waveoff + v - x;
        if (t < NB) { excl0[t] = excl; rank_[t] = excl; }
    }
    __syncthreads();
    if (t < NB && hist[t] > 0) gbase[t] = atomicAdd(&bucket_off[t], hist[t]);
    else if (t < NB)           gbase[t] = 0;
    #pragma unroll
    for (int k = 0; k < 8; ++k) {
        if (mybkt[k] >= 0) {
            int p = atomicAdd(&rank_[mybkt[k]], 1);
            stage[p] = myrec[k];
            bof[p]   = (unsigned short)mybkt[k];
        }
    }
    __syncthreads();
    for (int s = t; s < cnt; s += 1024) {
        int b = bof[s];
        rec[gbase[b] + (s - excl0[b])] = stage[s];   // coalesced runs per bucket
    }
}

// one block per bucket: local row hist + scan -> rowptr; scatter packed
// (col,w) csr within an L2-resident window.
__global__ void local_fill_kernel(const int* __restrict__ bucket_base,
                                  const int2* __restrict__ rec,
                                  int2* __restrict__ csr,
                                  int* __restrict__ rowptr)
{
    __shared__ int hist[RPB], off[RPB], ls[4];
    const int b = blockIdx.x, t = threadIdx.x;      // 256 threads
    const int lo = bucket_base[b], hi = bucket_base[b + 1];
    const int rows = (N_NODES - b * RPB < RPB) ? (N_NODES - b * RPB) : RPB;
    hist[t] = 0;
    __syncthreads();
    for (int s = lo + t; s < hi; s += 256)
        atomicAdd(&hist[rec[s].x >> 18], 1);
    __syncthreads();
    const int lane = t & 63, wv = t >> 6;
    int x = hist[t];
    int v = x;
    #pragma unroll
    for (int d = 1; d < 64; d <<= 1) { int y = __shfl_up(v, d, 64); if (lane >= d) v += y; }
    if (lane == 63) ls[wv] = v;
    __syncthreads();
    if (wv == 0 && lane < 4) {
        int s = ls[lane];
        #pragma unroll
        for (int d = 1; d < 4; d <<= 1) { int y = __shfl_up(s, d, 64); if (lane >= d) s += y; }
        ls[lane] = s;
    }
    __syncthreads();
    int waveoff = wv ? ls[wv - 1] : 0;
    int excl = waveoff + v - x;
    if (t < rows) rowptr[b * RPB + t] = lo + excl;
    off[t] = lo + excl;
    if (b == NB - 1 && t == 0) rowptr[N_NODES] = N_EDGES;
    __syncthreads();
    for (int s = lo + t; s < hi; s += 256) {
        int2 r = rec[s];
        int rl = r.x >> 18;
        int pos = atomicAdd(&off[rl], 1);
        csr[pos] = make_int2(r.x & 0x3FFFF, r.y);   // packed (col, w-bits)
    }
}

// ---------- gather hop core ----------
// lanes 0-31 even edges, 32-63 odd edges; lane owns dims {2*hl, 2*hl+1} as
// one packed uint (bf16 or fp16). Main loop: unpredicated 16-edge chunks,
// depth-2 pipeline. Tail: ONE predicated 16-slot step (clamp to e-1, w=0).

template <bool ISB>
__device__ __forceinline__ void gather_row(const int2* __restrict__ csr,
                                           const unsigned int* __restrict__ p,
                                           int s, int e, int half, int hl,
                                           float& alo_o, float& ahi_o)
{
    float lo[4] = {0.f, 0.f, 0.f, 0.f};
    float hi[4] = {0.f, 0.f, 0.f, 0.f};
    const int len   = e - s;
    const int nfull = len >> 4;          // full 16-edge chunks
    const int rem   = len & 15;

    int2 cwA[8], cwB[8];
    unsigned int vA[8], vB[8];

#define LD_CSR(cw, base)                                             \
    _Pragma("unroll")                                                \
    for (int u = 0; u < 8; ++u) (cw)[u] = csr[(base) + 2 * u + half];
#define GATHER(v, cw)                                                \
    _Pragma("unroll")                                                \
    for (int u = 0; u < 8; ++u)                                      \
        (v)[u] = p[(size_t)((unsigned int)(cw)[u].x * 32u + hl)];
#define FMA8(cw, v)                                                  \
    _Pragma("unroll")                                                \
    for (int u = 0; u < 8; ++u) {                                    \
        float w = __int_as_float((cw)[u].y);                         \
        float fx, fy;                                                \
        if (ISB) {                                                   \
            fx = __uint_as_float((v)[u] << 16);                      \
            fy = __uint_as_float((v)[u] & 0xffff0000u);              \
        } else {                                                     \
            float2 f2 = __half22float2(                              \
                *reinterpret_cast<const __half2*>(&(v)[u]));         \
            fx = f2.x; fy = f2.y;                                    \
        }                                                            \
        lo[u & 3] = fmaf(w, fx, lo[u & 3]);                          \
        hi[u & 3] = fmaf(w, fy, hi[u & 3]);                          \
    }

    if (nfull > 0) {
        LD_CSR(cwA, s);
        if (nfull > 1) LD_CSR(cwB, s + 16);
        GATHER(vA, cwA);
        int c = 0;
        while (true) {
            // chunk c in A, chunk c+1 in B
            if (c + 1 < nfull) GATHER(vB, cwB);
            FMA8(cwA, vA);
            if (c + 1 >= nfull) break;
            if (c + 2 < nfull) LD_CSR(cwA, s + (c + 2) * 16);
            ++c;
            // chunk c in B, chunk c+1 in A
            if (c + 1 < nfull) GATHER(vA, cwA);
            FMA8(cwB, vB);
            if (c + 1 >= nfull) break;
            if (c + 2 < nfull) LD_CSR(cwB, s + (c + 2) * 16);
            ++c;
        }
    }
    if (rem) {
        const int base = s + nfull * 16;
        int2 cw[8];
        #pragma unroll
        for (int u = 0; u < 8; ++u) {
            int idx = base + 2 * u + half;
            int j = (idx < e) ? idx : (e - 1);
            cw[u] = csr[j];
            if (idx >= e) cw[u].y = 0;     // w = 0 for padding slots
        }
        unsigned int v[8];
        #pragma unroll
        for (int u = 0; u < 8; ++u)
            v[u] = p[(size_t)((unsigned int)cw[u].x * 32u + hl)];
        FMA8(cw, v);
    }
#undef LD_CSR
#undef GATHER
#undef FMA8
    alo_o = (lo[0] + lo[1]) + (lo[2] + lo[3]);
    ahi_o = (hi[0] + hi[1]) + (hi[2] + hi[3]);
}

// LAST fuses epilogue: out = (emb0 + h1 + h2 + h3)/4.
template <bool LAST>
__global__ void hop_kernel(const int* __restrict__ rowptr,
                           const int2* __restrict__ csr,
                           const void* __restrict__ prev,
                           void* __restrict__ next,
                           const void* __restrict__ E0,   // emb0 (LAST only)
                           const void* __restrict__ H1,   // h1   (LAST only)
                           void* __restrict__ out,
                           const int* __restrict__ flag)
{
    int row  = blockIdx.x * (blockDim.x >> 6) + (threadIdx.x >> 6);
    if (row >= N_NODES) return;
    const int half = (threadIdx.x >> 5) & 1;
    const int hl   = threadIdx.x & 31;
    const bool isb = ((*flag) & 1);
    const int s = rowptr[row], e = rowptr[row + 1];
    const unsigned int* p = (const unsigned int*)prev;
    float alo, ahi;
    if (isb) gather_row<true >(csr, p, s, e, half, hl, alo, ahi);
    else     gather_row<false>(csr, p, s, e, half, hl, alo, ahi);
    alo += __shfl_xor(alo, 32);          // combine even/odd edge halves
    ahi += __shfl_xor(ahi, 32);
    if (half) return;                    // half 0 writes the full row
    size_t o32 = (size_t)row * 32 + hl;  // index in 2-element units
    if (LAST) {
        size_t oo = o32 + ((row < NUM_USERS) ? 0 : (size_t)(U_ELEMS / 2));
        unsigned int e0u = ((const unsigned int*)E0)[o32];
        unsigned int h1u = ((const unsigned int*)H1)[o32];
        unsigned int h2u = ((const unsigned int*)prev)[o32];
        if (isb) {
            float vlo = (__uint_as_float(e0u << 16) + __uint_as_float(h1u << 16) +
                         __uint_as_float(h2u << 16) + alo) * 0.25f;
            float vhi = (__uint_as_float(e0u & 0xffff0000u) + __uint_as_float(h1u & 0xffff0000u) +
                         __uint_as_float(h2u & 0xffff0000u) + ahi) * 0.25f;
            bf16 blo = __float2bfloat16(vlo), bhi = __float2bfloat16(vhi);
            ((unsigned int*)out)[oo] =
                ((unsigned int)(*reinterpret_cast<unsigned short*>(&bhi)) << 16) |
                (*reinterpret_cast<unsigned short*>(&blo));
        } else {
            float2 e0f = __half22float2(*reinterpret_cast<const __half2*>(&e0u));
            float2 h1f = __half22float2(*reinterpret_cast<const __half2*>(&h1u));
            float2 h2f = __half22float2(*reinterpret_cast<const __half2*>(&h2u));
            float2 v;
            v.x = (e0f.x + h1f.x + h2f.x + alo) * 0.25f;
            v.y = (e0f.y + h1f.y + h2f.y + ahi) * 0.25f;
            ((float2*)out)[oo] = v;
        }
    } else {
        if (isb) {
            bf16 blo = __float2bfloat16(alo), bhi = __float2bfloat16(ahi);
            ((unsigned int*)next)[o32] =
                ((unsigned int)(*reinterpret_cast<unsigned short*>(&bhi)) << 16) |
                (*reinterpret_cast<unsigned short*>(&blo));
        } else {
            __half2 h = __floats2half2_rn(alo, ahi);
            ((unsigned int*)next)[o32] = *reinterpret_cast<unsigned int*>(&h);
        }
    }
}

// ---------- R3 atomic fallback ----------

__global__ void init_kernel(const void* __restrict__ users,
                            const void* __restrict__ items,
                            void* __restrict__ out,
                            float* __restrict__ A,
                            float* __restrict__ B,
                            float* __restrict__ ACC,
                            const int* __restrict__ flag)
{
    int gid = blockIdx.x * blockDim.x + threadIdx.x;
    if (gid >= NODE_ELEMS) return;
    const bool isb = ((*flag) & 1);
    float v;
    if (gid < U_ELEMS) {
        if (isb) { bf16 b = ((const bf16*)users)[gid]; v = __bfloat162float(b); ((bf16*)out)[U_ELEMS + gid] = b; }
        else     { float fv = ((const float*)users)[gid]; v = fv; ((float*)out)[U_ELEMS + gid] = fv; }
    } else {
        int ii = gid - U_ELEMS;
        if (isb) { bf16 b = ((const bf16*)items)[ii]; v = __bfloat162float(b); ((bf16*)out)[2 * U_ELEMS + I_ELEMS + ii] = b; }
        else     { float fv = ((const float*)items)[ii]; v = fv; ((float*)out)[2 * U_ELEMS + I_ELEMS + ii] = fv; }
    }
    A[gid]   = v;
    B[gid]   = 0.0f;
    ACC[gid] = v;
}

__global__ void finalize_kernel(const float* __restrict__ acc,
                                void* __restrict__ out,
                                const int* __restrict__ flag)
{
    int gid = blockIdx.x * blockDim.x + threadIdx.x;
    if (gid >= NODE_ELEMS) return;
    const bool isb = ((*flag) & 1);
    float v = acc[gid] * 0.25f;
    size_t o = (gid < U_ELEMS) ? (size_t)gid : (size_t)(2 * U_ELEMS + (gid - U_ELEMS));
    if (isb) ((bf16*)out)[o]  = __float2bfloat16(v);
    else     ((float*)out)[o] = v;
}

__global__ void scatter_kernel(const int* __restrict__ ei32,
                               const void* __restrict__ ew,
                               const float* __restrict__ prev,
                               float* __restrict__ next,
                               const int* __restrict__ flag)
{
    int gid = blockIdx.x * blockDim.x + threadIdx.x;
    if (gid >= N_EDGES * 16) return;
    const int f = *flag;
    int e = gid >> 4;
    int j = (gid & 15) << 2;
    int row = load_row(ei32, f, e);
    int col = load_col(ei32, f, e);
    float w = load_w(ew, f, e);
    const float4 v = *reinterpret_cast<const float4*>(prev + (size_t)col * EMB + j);
    float* dst = next + (size_t)row * EMB + j;
    unsafeAtomicAdd(dst + 0, w * v.x);
    unsafeAtomicAdd(dst + 1, w * v.y);
    unsafeAtomicAdd(dst + 2, w * v.z);
    unsafeAtomicAdd(dst + 3, w * v.w);
}

__global__ void accum_zero_kernel(float* __restrict__ acc,
                                  const float* __restrict__ next,
                                  float* __restrict__ prevz)
{
    int gid = blockIdx.x * blockDim.x + threadIdx.x;
    if (gid >= NODE_ELEMS) return;
    acc[gid] += next[gid];
    prevz[gid] = 0.0f;
}

__global__ void sentinel_kernel(unsigned int* __restrict__ out, int nwords)
{
    int gid = blockIdx.x * blockDim.x + threadIdx.x;
    if (gid < nwords) out[gid] = 0x447A447Au;
}

extern "C" void kernel_launch(void* const* d_in, const int* in_sizes, int n_in,
                              void* d_out, int out_size, void* d_ws, size_t ws_size,
                              hipStream_t stream)
{
    const void* users = d_in[0];
    const void* items = d_in[1];
    const int*  ei32  = (const int*)d_in[2];
    const void* ew    = d_in[3];

    char* wsb  = (char*)d_ws;
    int*  flag = (int*)wsb;
    float* A   = (float*)(wsb + 256);              // fp32-sized; holds 16-bit in CSR path
    float* B   = A + (size_t)NODE_ELEMS;           // h1 buffer; aliases rec
    float* ACC = B + (size_t)NODE_ELEMS;           // h2 buffer in CSR path
    char* p    = (char*)(ACC + (size_t)NODE_ELEMS);
    int*  rowptr      = (int*)p;  p += (N_NODES + 4) * sizeof(int);
    int*  bucket_cnt  = (int*)p;  p += (NB + 2) * sizeof(int);
    int*  bucket_base = (int*)p;  p += (NB + 2) * sizeof(int);
    int*  bucket_off  = (int*)p;  p += (NB + 2) * sizeof(int);
    int2* csr         = (int2*)p; p += (size_t)N_EDGES * sizeof(int2);  // packed (col,w)
    int2* rec         = (int2*)B;                  // alias: dead before hop1 writes B

    const size_t need_csr    = (size_t)(p - wsb);                  // ~154.4 MB
    const size_t need_atomic = 256 + 3 * (size_t)NODE_ELEMS * sizeof(float);
    const int BLK = 256;
    const int node_blocks = (NODE_ELEMS + BLK - 1) / BLK;
    const int vec_blocks  = (NODE_ELEMS / 4 + BLK - 1) / BLK;
    const int row_blocks  = (N_NODES + 3) / 4;       // 4 rows (waves) per block
    const int bin_blocks  = (N_EDGES + EPB - 1) / EPB;   // 586

    if (ws_size >= need_csr) {
        float* C = ACC;   // h2 buffer
        detect_kernel<<<1, BLK, 0, stream>>>((const unsigned short*)users, ei32, flag, bucket_cnt);
        init_vec_kernel<<<vec_blocks, BLK, 0, stream>>>(users, items, d_out, A, flag);
        bucket_hist_kernel<<<1024, BLK, 0, stream>>>(ei32, bucket_cnt, flag);
        bucket_scan_kernel<<<1, 1024, 0, stream>>>(bucket_cnt, bucket_base, bucket_off);
        bin_kernel<<<bin_blocks, 1024, 0, stream>>>(ei32, ew, bucket_off, rec, flag);
        local_fill_kernel<<<NB, RPB, 0, stream>>>(bucket_base, rec, csr, rowptr);

        // hop1: A(emb0) -> B(h1); hop2: B -> C(h2); hop3: C -> out, fusing
        // out = (A + B + C + h3)/4 in the epilogue.
        hop_kernel<false><<<row_blocks, BLK, 0, stream>>>(rowptr, csr, A, B, nullptr, nullptr, nullptr, flag);
        hop_kernel<false><<<row_blocks, BLK, 0, stream>>>(rowptr, csr, B, C, nullptr, nullptr, nullptr, flag);
        hop_kernel<true ><<<row_blocks, BLK, 0, stream>>>(rowptr, csr, C, nullptr, A, B, d_out, flag);
    } else if (ws_size >= need_atomic) {
        const int sedge_blocks = (N_EDGES * 16 + BLK - 1) / BLK;
        detect_kernel<<<1, BLK, 0, stream>>>((const unsigned short*)users, ei32, flag, bucket_cnt);
        init_kernel<<<node_blocks, BLK, 0, stream>>>(users, items, d_out, A, B, ACC, flag);
        float* prev = A;
        float* nxt  = B;
        for (int h = 0; h < 3; ++h) {
            scatter_kernel<<<sedge_blocks, BLK, 0, stream>>>(ei32, ew, prev, nxt, flag);
            accum_zero_kernel<<<node_blocks, BLK, 0, stream>>>(ACC, nxt, prev);
            float* t = prev; prev = nxt; nxt = t;
        }
        finalize_kernel<<<node_blocks, BLK, 0, stream>>>(ACC, d_out, flag);
    } else {
        int nwords = out_size / 2;
        sentinel_kernel<<<(nwords + BLK - 1) / BLK, BLK, 0, stream>>>((unsigned int*)d_out, nwords);
    }
}